// Round 5
// baseline (174.444 us; speedup 1.0000x reference)
//
#include <hip/hip_runtime.h>
#include <hip/hip_bf16.h>
#include <stdint.h>

// Shapes (fixed by the problem)
#define B_ROWS 16384
#define VDIM   16
#define SDIM   64
#define HDIM   512
#define KDIM   1024   // V*S
#define KP     1056   // KDIM + 16 bias cols + 16 zero pad (multiple of 32)
#define ASTR   1064   // LDS A' row stride in elems (1056 + 8 pad)
#define K2_LDS (32 * ASTR * 2)   // 68096 B dynamic LDS -> 2 blocks/CU

using bf16x8 = __attribute__((ext_vector_type(8))) __bf16;
using u16x8  = __attribute__((ext_vector_type(8))) unsigned short;
using f32x4  = __attribute__((ext_vector_type(4))) float;

__device__ __forceinline__ unsigned short f2bf(float f) {
  unsigned int u = __builtin_bit_cast(unsigned int, f);
  u = (u + 0x7FFFu + ((u >> 16) & 1u)) >> 16;   // RNE
  return (unsigned short)u;
}

// ---------------------------------------------------------------------------
// K0 (merged): blocks [0,2112): build Bt = [W_cat ; bias ; 0]^T bf16 [HDIM][KP]
//              blocks [2112,2368): WcombT rows (no LDS: Wsel read as float4,
//              L1/L2-resident 32 KB);  block 2368: bcomb.
__global__ __launch_bounds__(256) void k0_prep(
    const float* __restrict__ W, const float* __restrict__ bias,
    const float* __restrict__ Wsel, const float* __restrict__ bsel,
    unsigned short* __restrict__ Bt, unsigned short* __restrict__ WcombT,
    float* __restrict__ bcomb) {
  __shared__ float bm[HDIM];
  __shared__ float part[16][17];
  const int t = threadIdx.x;
  if (blockIdx.x < 2112) {
    int idx = blockIdx.x * 256 + t;    // 1056*512 = 540672 exactly
    int k = idx >> 9;                  // 0..1055
    int n = idx & 511;                 // 0..511
    float val;
    if (k < KDIM)            val = W[(size_t)k * HDIM + n];
    else if (k < KDIM + 16)  val = bias[(size_t)(k - KDIM) * HDIM + n];
    else                     val = 0.f;
    Bt[(size_t)n * KP + k] = f2bf(val);
    return;
  }
  const int bid = blockIdx.x - 2112;   // 0..256
  if (bid < 256) {
    const int wave = t >> 6, lane = t & 63;
    const int k = bid * 4 + wave;
    const float* wr = W + (size_t)k * HDIM;
    float s[16];
    #pragma unroll
    for (int v = 0; v < 16; ++v) s[v] = 0.f;
    #pragma unroll
    for (int j = 0; j < 8; ++j) {
      const int h = lane + 64 * j;
      const float a = wr[h];
      const float4* wl = (const float4*)(Wsel + h * 16);
      const float4 q0 = wl[0], q1 = wl[1], q2 = wl[2], q3 = wl[3];
      s[0]  = fmaf(a, q0.x, s[0]);  s[1]  = fmaf(a, q0.y, s[1]);
      s[2]  = fmaf(a, q0.z, s[2]);  s[3]  = fmaf(a, q0.w, s[3]);
      s[4]  = fmaf(a, q1.x, s[4]);  s[5]  = fmaf(a, q1.y, s[5]);
      s[6]  = fmaf(a, q1.z, s[6]);  s[7]  = fmaf(a, q1.w, s[7]);
      s[8]  = fmaf(a, q2.x, s[8]);  s[9]  = fmaf(a, q2.y, s[9]);
      s[10] = fmaf(a, q2.z, s[10]); s[11] = fmaf(a, q2.w, s[11]);
      s[12] = fmaf(a, q3.x, s[12]); s[13] = fmaf(a, q3.y, s[13]);
      s[14] = fmaf(a, q3.z, s[14]); s[15] = fmaf(a, q3.w, s[15]);
    }
    #pragma unroll
    for (int off = 32; off > 0; off >>= 1) {
      #pragma unroll
      for (int v = 0; v < 16; ++v) s[v] += __shfl_xor(s[v], off, 64);
    }
    float mine = 0.f;
    #pragma unroll
    for (int v = 0; v < 16; ++v) mine = (lane == v) ? s[v] : mine;
    if (lane < 16) WcombT[lane * KDIM + k] = f2bf(mine * (1.f / 16.f));
  } else {
    for (int h = t; h < HDIM; h += 256) {
      float s = 0.f;
      #pragma unroll
      for (int v = 0; v < VDIM; ++v) s += bias[v * HDIM + h];
      bm[h] = s * (1.f / 16.f);
    }
    __syncthreads();
    int v = t & 15, sl = t >> 4;
    float s = 0.f;
    for (int h = sl * 32; h < sl * 32 + 32; ++h) s = fmaf(bm[h], Wsel[h * VDIM + v], s);
    part[sl][v] = s;
    __syncthreads();
    if (t < 16) {
      float s2 = bsel[t];
      #pragma unroll
      for (int i = 0; i < 16; ++i) s2 += part[i][t];
      bcomb[t] = s2;
    }
  }
}

// ---------------------------------------------------------------------------
// K1a: partial logits via MFMA, no LDS, no shuffles.
// wave = (row-tile rt of 16 rows, K-segment seg of 256). 4096 waves.
__global__ __launch_bounds__(256) void k1a_logits(
    const float* __restrict__ x, const unsigned short* __restrict__ WcombT,
    float* __restrict__ part) {
  const int gw = blockIdx.x * 4 + (threadIdx.x >> 6);
  const int lane = threadIdx.x & 63;
  const int rt = gw >> 2, seg = gw & 3;
  const int m = lane & 15, quad = lane >> 4;
  const float* xr = x + (size_t)(rt * 16 + m) * KDIM + seg * 256 + quad * 8;
  const unsigned short* br = WcombT + m * KDIM + seg * 256 + quad * 8;
  f32x4 acc = {0.f, 0.f, 0.f, 0.f};
  #pragma unroll
  for (int kt = 0; kt < 8; ++kt) {
    float4 a0 = *(const float4*)(xr);
    float4 a1 = *(const float4*)(xr + 4);
    xr += 32;
    u16x8 u;
    u[0] = f2bf(a0.x); u[1] = f2bf(a0.y); u[2] = f2bf(a0.z); u[3] = f2bf(a0.w);
    u[4] = f2bf(a1.x); u[5] = f2bf(a1.y); u[6] = f2bf(a1.z); u[7] = f2bf(a1.w);
    bf16x8 af = __builtin_bit_cast(bf16x8, u);
    bf16x8 bfv = *(const bf16x8*)(br);
    br += 32;
    acc = __builtin_amdgcn_mfma_f32_16x16x32_bf16(af, bfv, acc, 0, 0, 0);
  }
  float* pr = part + (size_t)(rt * 16 + quad * 4) * 64 + seg * 16 + m;
  #pragma unroll
  for (int r = 0; r < 4; ++r) pr[(size_t)r * 64] = acc[r];
}

// ---------------------------------------------------------------------------
// K1b0: thread-per-row softmax -> wts[row][16] fp32 only.
__global__ __launch_bounds__(256) void k1b0_softmax(
    const float* __restrict__ part, const float* __restrict__ bcomb,
    float* __restrict__ weights) {
  const int row = blockIdx.x * 256 + threadIdx.x;
  const float* p = part + (size_t)row * 64;
  float l[16];
  float mx = -1e30f;
  #pragma unroll
  for (int v = 0; v < 16; ++v) {
    l[v] = bcomb[v] + p[v] + p[16 + v] + p[32 + v] + p[48 + v];
    mx = fmaxf(mx, l[v]);
  }
  float s = 0.f;
  #pragma unroll
  for (int v = 0; v < 16; ++v) { l[v] = __expf(l[v] - mx); s += l[v]; }
  const float inv = 1.f / s;
  float4* wout = (float4*)(weights + (size_t)row * 16);
  #pragma unroll
  for (int q = 0; q < 4; ++q) {
    float4 f;
    f.x = l[4 * q + 0] * inv; f.y = l[4 * q + 1] * inv;
    f.z = l[4 * q + 2] * inv; f.w = l[4 * q + 3] * inv;
    wout[q] = f;
  }
}

// ---------------------------------------------------------------------------
// K2f: fused scale+GEMM, block M32 x N512 (full width: x read once).
// 68 KB dynamic LDS -> 2 blocks/CU, grid 512, 16 waves/CU (4/SIMD).
// 8 waves, wave-tile 32x64. Single barrier; barrier-free K-loop with explicit
// register double-buffer on the B fragments (L2 latency always covered).
__global__ __launch_bounds__(512, 4) void k2f_gemm(
    const float* __restrict__ x, const float* __restrict__ wts,
    const unsigned short* __restrict__ Bt, float* __restrict__ C) {
  extern __shared__ unsigned short As[];   // [32][ASTR]

  const int t = threadIdx.x;
  const int rowb = blockIdx.x * 32;

  // ---- staging: 16 threads per row; thread covers k = (t&15)*4 + i*64
  {
    const int srow = t >> 4;              // 0..31
    const int sc = (t & 15) * 4;          // 0,4,...,60
    const float* xr = x + (size_t)(rowb + srow) * KDIM + sc;
    const float* wr = wts + (size_t)(rowb + srow) * 16;
    float wv[16];
    #pragma unroll
    for (int q = 0; q < 4; ++q) {
      float4 f = ((const float4*)wr)[q];
      wv[4 * q + 0] = f.x; wv[4 * q + 1] = f.y; wv[4 * q + 2] = f.z; wv[4 * q + 3] = f.w;
    }
    unsigned short* aw = As + srow * ASTR + sc;
    #pragma unroll 4
    for (int i = 0; i < 16; ++i) {
      const float4 a = *(const float4*)(xr + i * 64);
      const float w = wv[i];              // v = k>>6 = i (sc < 64)
      unsigned short o[4];
      o[0] = f2bf(w * a.x); o[1] = f2bf(w * a.y);
      o[2] = f2bf(w * a.z); o[3] = f2bf(w * a.w);
      *(uint2*)(aw + i * 64) = *(const uint2*)o;
    }
    // bias tail: A'[row][1024+j] = bf16(w[j]) for j<16 else 0
    if ((t & 15) < 4) {
      const int j8 = (t & 15) * 8;        // 0,8,16,24
      unsigned short o[8];
      #pragma unroll
      for (int jj = 0; jj < 8; ++jj)
        o[jj] = (j8 + jj < 16) ? f2bf(wv[j8 + jj]) : (unsigned short)0;
      *(u16x8*)(As + srow * ASTR + KDIM + j8) = *(const u16x8*)o;
    }
  }

  // ---- B pointers + first-iter B prefetch issued BEFORE the barrier
  const int wave = t >> 6, lane = t & 63;
  const int mlane = lane & 15, quad = lane >> 4;
  const int colb = wave * 64;

  const unsigned short* bp[4];
  #pragma unroll
  for (int j = 0; j < 4; ++j)
    bp[j] = Bt + (size_t)(colb + j * 16 + mlane) * KP + quad * 8;

  bf16x8 bv[4];
  #pragma unroll
  for (int j = 0; j < 4; ++j) { bv[j] = *(const bf16x8*)bp[j]; bp[j] += 32; }

  __syncthreads();   // the ONLY barrier

  const unsigned short* ap[2];
  #pragma unroll
  for (int i = 0; i < 2; ++i)
    ap[i] = As + (i * 16 + mlane) * ASTR + quad * 8;

  f32x4 acc[2][4];
  const f32x4 z = {0.f, 0.f, 0.f, 0.f};
  #pragma unroll
  for (int i = 0; i < 2; ++i)
    #pragma unroll
    for (int j = 0; j < 4; ++j) acc[i][j] = z;

  #pragma unroll 1
  for (int kt = 0; kt < 33; ++kt) {
    // prefetch next-iter B while this iter's MFMAs run
    bf16x8 bnext[4];
    if (kt < 32) {
      #pragma unroll
      for (int j = 0; j < 4; ++j) { bnext[j] = *(const bf16x8*)bp[j]; bp[j] += 32; }
    }
    bf16x8 av[2];
    #pragma unroll
    for (int i = 0; i < 2; ++i) { av[i] = *(const bf16x8*)ap[i]; ap[i] += 32; }
    #pragma unroll
    for (int i = 0; i < 2; ++i)
      #pragma unroll
      for (int j = 0; j < 4; ++j)
        acc[i][j] = __builtin_amdgcn_mfma_f32_16x16x32_bf16(av[i], bv[j], acc[i][j], 0, 0, 0);
    #pragma unroll
    for (int j = 0; j < 4; ++j) bv[j] = bnext[j];
  }

  // ---- epilogue: C/D layout col=lane&15, row=quad*4+reg  [m89/m91]
  #pragma unroll
  for (int i = 0; i < 2; ++i)
    #pragma unroll
    for (int j = 0; j < 4; ++j)
      #pragma unroll
      for (int r = 0; r < 4; ++r) {
        const size_t row = (size_t)rowb + i * 16 + quad * 4 + r;
        const int col = colb + j * 16 + mlane;
        C[row * HDIM + col] = acc[i][j][r];
      }
}

// ---------------------------------------------------------------------------
extern "C" void kernel_launch(void* const* d_in, const int* in_sizes, int n_in,
                              void* d_out, int out_size, void* d_ws, size_t ws_size,
                              hipStream_t stream) {
  const float* x    = (const float*)d_in[0];   // [B, V, S] = [16384][1024] flat
  const float* W    = (const float*)d_in[1];   // [V, S, H] = [1024][512] flat
  const float* bias = (const float*)d_in[2];   // [V, H]
  const float* Wsel = (const float*)d_in[3];   // [H, V]
  const float* bsel = (const float*)d_in[4];   // [V]
  float* out = (float*)d_out;                  // [B, H] fp32

  char* ws = (char*)d_ws;
  unsigned short* Bt     = (unsigned short*)(ws);            // 512*1056*2 = 1,081,344 B
  unsigned short* WcombT = (unsigned short*)(ws + 1081344);  // 16*1024*2  =    32,768 B
  float*          bcomb  = (float*)(ws + 1114112);           // 16*4 (padded to 256)
  float*          part   = (float*)(ws + 1114368);           // 16384*64*4 = 4,194,304 B
  float*          wts    = (float*)(ws + 5308672);           // 16384*16*4 = 1,048,576 B

  static int lds_set = 0;
  if (!lds_set) {
    hipFuncSetAttribute((const void*)k2f_gemm,
                        hipFuncAttributeMaxDynamicSharedMemorySize, K2_LDS);
    lds_set = 1;
  }

  k0_prep<<<2369, 256, 0, stream>>>(W, bias, Wsel, bsel, Bt, WcombT, bcomb);
  k1a_logits<<<1024, 256, 0, stream>>>(x, WcombT, part);
  k1b0_softmax<<<64, 256, 0, stream>>>(part, bcomb, wts);
  k2f_gemm<<<512, 512, K2_LDS, stream>>>(x, wts, Bt, out);
}

// Round 6
// 162.883 us; speedup vs baseline: 1.0710x; 1.0710x over previous
//
#include <hip/hip_runtime.h>
#include <hip/hip_bf16.h>
#include <stdint.h>

// Shapes (fixed by the problem)
#define B_ROWS 16384
#define VDIM   16
#define SDIM   64
#define HDIM   512
#define KDIM   1024   // V*S
#define KP     1056   // KDIM + 16 bias cols + 16 zero pad (multiple of 32)
#define ASTR   1064   // LDS A' row stride in elems (1056 + 8 pad)
#define K2_LDS (64 * ASTR * 2)   // 136192 B dynamic LDS -> 1 block/CU, M64

using bf16x8 = __attribute__((ext_vector_type(8))) __bf16;
using u16x8  = __attribute__((ext_vector_type(8))) unsigned short;
using f32x4  = __attribute__((ext_vector_type(4))) float;

__device__ __forceinline__ unsigned short f2bf(float f) {
  unsigned int u = __builtin_bit_cast(unsigned int, f);
  u = (u + 0x7FFFu + ((u >> 16) & 1u)) >> 16;   // RNE
  return (unsigned short)u;
}
__device__ __forceinline__ float bf2f(unsigned short s) {
  return __builtin_bit_cast(float, (unsigned int)s << 16);
}

// ---------------------------------------------------------------------------
// K0 (merged): blocks [0,2112): build Bt = [W_cat ; bias ; 0]^T bf16 [HDIM][KP]
//              blocks [2112,2368): WcombT rows; block 2368: bcomb.
__global__ __launch_bounds__(256) void k0_prep(
    const float* __restrict__ W, const float* __restrict__ bias,
    const float* __restrict__ Wsel, const float* __restrict__ bsel,
    unsigned short* __restrict__ Bt, unsigned short* __restrict__ WcombT,
    float* __restrict__ bcomb) {
  __shared__ float bm[HDIM];
  __shared__ float part[16][17];
  const int t = threadIdx.x;
  if (blockIdx.x < 2112) {
    int idx = blockIdx.x * 256 + t;    // 1056*512 = 540672 exactly
    int k = idx >> 9;                  // 0..1055
    int n = idx & 511;                 // 0..511
    float val;
    if (k < KDIM)            val = W[(size_t)k * HDIM + n];
    else if (k < KDIM + 16)  val = bias[(size_t)(k - KDIM) * HDIM + n];
    else                     val = 0.f;
    Bt[(size_t)n * KP + k] = f2bf(val);
    return;
  }
  const int bid = blockIdx.x - 2112;   // 0..256
  if (bid < 256) {
    const int wave = t >> 6, lane = t & 63;
    const int k = bid * 4 + wave;
    const float* wr = W + (size_t)k * HDIM;
    float s[16];
    #pragma unroll
    for (int v = 0; v < 16; ++v) s[v] = 0.f;
    #pragma unroll
    for (int j = 0; j < 8; ++j) {
      const int h = lane + 64 * j;
      const float a = wr[h];
      const float4* wl = (const float4*)(Wsel + h * 16);
      const float4 q0 = wl[0], q1 = wl[1], q2 = wl[2], q3 = wl[3];
      s[0]  = fmaf(a, q0.x, s[0]);  s[1]  = fmaf(a, q0.y, s[1]);
      s[2]  = fmaf(a, q0.z, s[2]);  s[3]  = fmaf(a, q0.w, s[3]);
      s[4]  = fmaf(a, q1.x, s[4]);  s[5]  = fmaf(a, q1.y, s[5]);
      s[6]  = fmaf(a, q1.z, s[6]);  s[7]  = fmaf(a, q1.w, s[7]);
      s[8]  = fmaf(a, q2.x, s[8]);  s[9]  = fmaf(a, q2.y, s[9]);
      s[10] = fmaf(a, q2.z, s[10]); s[11] = fmaf(a, q2.w, s[11]);
      s[12] = fmaf(a, q3.x, s[12]); s[13] = fmaf(a, q3.y, s[13]);
      s[14] = fmaf(a, q3.z, s[14]); s[15] = fmaf(a, q3.w, s[15]);
    }
    #pragma unroll
    for (int off = 32; off > 0; off >>= 1) {
      #pragma unroll
      for (int v = 0; v < 16; ++v) s[v] += __shfl_xor(s[v], off, 64);
    }
    float mine = 0.f;
    #pragma unroll
    for (int v = 0; v < 16; ++v) mine = (lane == v) ? s[v] : mine;
    if (lane < 16) WcombT[lane * KDIM + k] = f2bf(mine * (1.f / 16.f));
  } else {
    for (int h = t; h < HDIM; h += 256) {
      float s = 0.f;
      #pragma unroll
      for (int v = 0; v < VDIM; ++v) s += bias[v * HDIM + h];
      bm[h] = s * (1.f / 16.f);
    }
    __syncthreads();
    int v = t & 15, sl = t >> 4;
    float s = 0.f;
    for (int h = sl * 32; h < sl * 32 + 32; ++h) s = fmaf(bm[h], Wsel[h * VDIM + v], s);
    part[sl][v] = s;
    __syncthreads();
    if (t < 16) {
      float s2 = bsel[t];
      #pragma unroll
      for (int i = 0; i < 16; ++i) s2 += part[i][t];
      bcomb[t] = s2;
    }
  }
}

// ---------------------------------------------------------------------------
// K1a: partial logits via MFMA + emit xb = bf16(x) as a side product
// (k2f stages from xb: half the bytes, L3-warm). 4096 waves.
__global__ __launch_bounds__(256) void k1a_logits(
    const float* __restrict__ x, const unsigned short* __restrict__ WcombT,
    float* __restrict__ part, unsigned short* __restrict__ xb) {
  const int gw = blockIdx.x * 4 + (threadIdx.x >> 6);
  const int lane = threadIdx.x & 63;
  const int rt = gw >> 2, seg = gw & 3;
  const int m = lane & 15, quad = lane >> 4;
  const size_t off0 = (size_t)(rt * 16 + m) * KDIM + seg * 256 + quad * 8;
  const float* xr = x + off0;
  unsigned short* xw = xb + off0;
  const unsigned short* br = WcombT + m * KDIM + seg * 256 + quad * 8;
  f32x4 acc = {0.f, 0.f, 0.f, 0.f};
  #pragma unroll
  for (int kt = 0; kt < 8; ++kt) {
    float4 a0 = *(const float4*)(xr);
    float4 a1 = *(const float4*)(xr + 4);
    xr += 32;
    u16x8 u;
    u[0] = f2bf(a0.x); u[1] = f2bf(a0.y); u[2] = f2bf(a0.z); u[3] = f2bf(a0.w);
    u[4] = f2bf(a1.x); u[5] = f2bf(a1.y); u[6] = f2bf(a1.z); u[7] = f2bf(a1.w);
    *(u16x8*)xw = u;                   // 16-B store; 4 lanes/row -> 64-B segs
    xw += 32;
    bf16x8 af = __builtin_bit_cast(bf16x8, u);
    bf16x8 bfv = *(const bf16x8*)(br);
    br += 32;
    acc = __builtin_amdgcn_mfma_f32_16x16x32_bf16(af, bfv, acc, 0, 0, 0);
  }
  float* pr = part + (size_t)(rt * 16 + quad * 4) * 64 + seg * 16 + m;
  #pragma unroll
  for (int r = 0; r < 4; ++r) pr[(size_t)r * 64] = acc[r];
}

// ---------------------------------------------------------------------------
// K1b0: thread-per-row softmax -> wts[row][16] fp32 only.
__global__ __launch_bounds__(256) void k1b0_softmax(
    const float* __restrict__ part, const float* __restrict__ bcomb,
    float* __restrict__ weights) {
  const int row = blockIdx.x * 256 + threadIdx.x;
  const float* p = part + (size_t)row * 64;
  float l[16];
  float mx = -1e30f;
  #pragma unroll
  for (int v = 0; v < 16; ++v) {
    l[v] = bcomb[v] + p[v] + p[16 + v] + p[32 + v] + p[48 + v];
    mx = fmaxf(mx, l[v]);
  }
  float s = 0.f;
  #pragma unroll
  for (int v = 0; v < 16; ++v) { l[v] = __expf(l[v] - mx); s += l[v]; }
  const float inv = 1.f / s;
  float4* wout = (float4*)(weights + (size_t)row * 16);
  #pragma unroll
  for (int q = 0; q < 4; ++q) {
    float4 f;
    f.x = l[4 * q + 0] * inv; f.y = l[4 * q + 1] * inv;
    f.z = l[4 * q + 2] * inv; f.w = l[4 * q + 3] * inv;
    wout[q] = f;
  }
}

// ---------------------------------------------------------------------------
// K2f: fused scale+GEMM, block M64 x N512 (R4 config: best measured).
// 136 KB LDS, grid 256 = 1 block/CU. Stage from xb (bf16, L3-warm, half the
// bytes of R4). Single barrier; barrier-free K-loop with 2-deep B register
// prefetch (covers ~220-cyc L2 latency; 1-deep was marginal).
__global__ __launch_bounds__(512, 2) void k2f_gemm(
    const unsigned short* __restrict__ xb, const float* __restrict__ wts,
    const unsigned short* __restrict__ Bt, float* __restrict__ C) {
  extern __shared__ unsigned short As[];   // [64][ASTR]

  const int t = threadIdx.x;
  const int rowb = blockIdx.x * 64;

  // ---- staging: 8 threads per row; thread covers k = (t&7)*8 + i*64
  {
    const int srow = t >> 3;              // 0..63
    const int sc = (t & 7) * 8;           // 0,8,...,56
    const unsigned short* xr = xb + (size_t)(rowb + srow) * KDIM + sc;
    const float* wr = wts + (size_t)(rowb + srow) * 16;
    float wv[16];
    #pragma unroll
    for (int q = 0; q < 4; ++q) {
      float4 f = ((const float4*)wr)[q];
      wv[4 * q + 0] = f.x; wv[4 * q + 1] = f.y; wv[4 * q + 2] = f.z; wv[4 * q + 3] = f.w;
    }
    unsigned short* aw = As + srow * ASTR + sc;
    #pragma unroll 4
    for (int i = 0; i < 16; ++i) {
      const u16x8 a = *(const u16x8*)(xr + i * 64);
      const float w = wv[i];              // v = k>>6 = i (sc < 64)
      u16x8 o;
      #pragma unroll
      for (int j = 0; j < 8; ++j) o[j] = f2bf(w * bf2f(a[j]));
      *(u16x8*)(aw + i * 64) = o;
    }
    // bias tail: A'[row][1024+j] = bf16(w[j]) for j<16 else 0
    if ((t & 7) < 4) {
      const int j8 = (t & 7) * 8;         // 0,8,16,24
      unsigned short o[8];
      #pragma unroll
      for (int jj = 0; jj < 8; ++jj)
        o[jj] = (j8 + jj < 16) ? f2bf(wv[j8 + jj]) : (unsigned short)0;
      *(u16x8*)(As + srow * ASTR + KDIM + j8) = *(const u16x8*)o;
    }
  }

  // ---- B pointers + 2-deep prefetch (iters 0,1) issued BEFORE the barrier
  const int wave = t >> 6, lane = t & 63;
  const int mlane = lane & 15, quad = lane >> 4;
  const int colb = wave * 64;

  const unsigned short* bp[4];
  #pragma unroll
  for (int j = 0; j < 4; ++j)
    bp[j] = Bt + (size_t)(colb + j * 16 + mlane) * KP + quad * 8;

  bf16x8 bv0[4], bv1[4];
  #pragma unroll
  for (int j = 0; j < 4; ++j) {
    bv0[j] = *(const bf16x8*)(bp[j]);
    bv1[j] = *(const bf16x8*)(bp[j] + 32);
    bp[j] += 64;
  }

  __syncthreads();   // the ONLY barrier

  const unsigned short* ap[4];
  #pragma unroll
  for (int i = 0; i < 4; ++i)
    ap[i] = As + (i * 16 + mlane) * ASTR + quad * 8;

  f32x4 acc[4][4];
  const f32x4 z = {0.f, 0.f, 0.f, 0.f};
  #pragma unroll
  for (int i = 0; i < 4; ++i)
    #pragma unroll
    for (int j = 0; j < 4; ++j) acc[i][j] = z;

  #pragma unroll 1
  for (int kt = 0; kt < 33; ++kt) {
    bf16x8 bnext[4];
    if (kt < 31) {
      #pragma unroll
      for (int j = 0; j < 4; ++j) { bnext[j] = *(const bf16x8*)bp[j]; bp[j] += 32; }
    }
    bf16x8 av[4];
    #pragma unroll
    for (int i = 0; i < 4; ++i) { av[i] = *(const bf16x8*)ap[i]; ap[i] += 32; }
    #pragma unroll
    for (int i = 0; i < 4; ++i)
      #pragma unroll
      for (int j = 0; j < 4; ++j)
        acc[i][j] = __builtin_amdgcn_mfma_f32_16x16x32_bf16(av[i], bv0[j], acc[i][j], 0, 0, 0);
    #pragma unroll
    for (int j = 0; j < 4; ++j) { bv0[j] = bv1[j]; bv1[j] = bnext[j]; }
  }

  // ---- epilogue: C/D layout col=lane&15, row=quad*4+reg  [m89/m91]
  #pragma unroll
  for (int i = 0; i < 4; ++i)
    #pragma unroll
    for (int j = 0; j < 4; ++j)
      #pragma unroll
      for (int r = 0; r < 4; ++r) {
        const size_t row = (size_t)rowb + i * 16 + quad * 4 + r;
        const int col = colb + j * 16 + mlane;
        C[row * HDIM + col] = acc[i][j][r];
      }
}

// ---------------------------------------------------------------------------
extern "C" void kernel_launch(void* const* d_in, const int* in_sizes, int n_in,
                              void* d_out, int out_size, void* d_ws, size_t ws_size,
                              hipStream_t stream) {
  const float* x    = (const float*)d_in[0];   // [B, V, S] = [16384][1024] flat
  const float* W    = (const float*)d_in[1];   // [V, S, H] = [1024][512] flat
  const float* bias = (const float*)d_in[2];   // [V, H]
  const float* Wsel = (const float*)d_in[3];   // [H, V]
  const float* bsel = (const float*)d_in[4];   // [V]
  float* out = (float*)d_out;                  // [B, H] fp32

  char* ws = (char*)d_ws;
  unsigned short* Bt     = (unsigned short*)(ws);            // 512*1056*2 = 1,081,344 B
  unsigned short* WcombT = (unsigned short*)(ws + 1081344);  // 16*1024*2  =    32,768 B
  float*          bcomb  = (float*)(ws + 1114112);           // 16*4 (padded to 256)
  float*          part   = (float*)(ws + 1114368);           // 16384*64*4 = 4,194,304 B
  float*          wts    = (float*)(ws + 5308672);           // 16384*16*4 = 1,048,576 B
  unsigned short* xbb    = (unsigned short*)(ws + 6357248);  // 16384*1024*2 = 33,554,432 B

  static int lds_set = 0;
  if (!lds_set) {
    hipFuncSetAttribute((const void*)k2f_gemm,
                        hipFuncAttributeMaxDynamicSharedMemorySize, K2_LDS);
    lds_set = 1;
  }

  k0_prep<<<2369, 256, 0, stream>>>(W, bias, Wsel, bsel, Bt, WcombT, bcomb);
  k1a_logits<<<1024, 256, 0, stream>>>(x, WcombT, part, xbb);
  k1b0_softmax<<<64, 256, 0, stream>>>(part, bcomb, wts);
  k2f_gemm<<<256, 512, K2_LDS, stream>>>(xbb, wts, Bt, out);
}

// Round 7
// 152.567 us; speedup vs baseline: 1.1434x; 1.0676x over previous
//
#include <hip/hip_runtime.h>
#include <hip/hip_bf16.h>
#include <stdint.h>

// Shapes (fixed by the problem)
#define B_ROWS 16384
#define VDIM   16
#define SDIM   64
#define HDIM   512
#define KDIM   1024   // V*S
#define KP     1056   // KDIM + 16 bias cols + 16 zero pad (multiple of 32)
#define ASTR   1064   // LDS A' row stride in elems (1056 + 8 pad)
// LDS: As 64*1064*2 = 136192 | plog 2*4*16*17*4 = 8704 | wlds 64*16*4 = 4096
#define PLOG_OFF 136192
#define WLDS_OFF (136192 + 8704)
#define K2_LDS   (136192 + 8704 + 4096)   // 148992 B -> 1 block/CU

using bf16x8 = __attribute__((ext_vector_type(8))) __bf16;
using u16x8  = __attribute__((ext_vector_type(8))) unsigned short;
using f32x4  = __attribute__((ext_vector_type(4))) float;

__device__ __forceinline__ unsigned short f2bf(float f) {
  unsigned int u = __builtin_bit_cast(unsigned int, f);
  u = (u + 0x7FFFu + ((u >> 16) & 1u)) >> 16;   // RNE
  return (unsigned short)u;
}
__device__ __forceinline__ float bf2f(unsigned short s) {
  return __builtin_bit_cast(float, (unsigned int)s << 16);
}

// ---------------------------------------------------------------------------
// K0 (merged): blocks [0,2112): build Bt = [W_cat ; bias ; 0]^T bf16 [HDIM][KP]
//              blocks [2112,2368): WcombT rows; block 2368: bcomb.
__global__ __launch_bounds__(256) void k0_prep(
    const float* __restrict__ W, const float* __restrict__ bias,
    const float* __restrict__ Wsel, const float* __restrict__ bsel,
    unsigned short* __restrict__ Bt, unsigned short* __restrict__ WcombT,
    float* __restrict__ bcomb) {
  __shared__ float bm[HDIM];
  __shared__ float part[16][17];
  const int t = threadIdx.x;
  if (blockIdx.x < 2112) {
    int idx = blockIdx.x * 256 + t;    // 1056*512 = 540672 exactly
    int k = idx >> 9;                  // 0..1055
    int n = idx & 511;                 // 0..511
    float val;
    if (k < KDIM)            val = W[(size_t)k * HDIM + n];
    else if (k < KDIM + 16)  val = bias[(size_t)(k - KDIM) * HDIM + n];
    else                     val = 0.f;
    Bt[(size_t)n * KP + k] = f2bf(val);
    return;
  }
  const int bid = blockIdx.x - 2112;   // 0..256
  if (bid < 256) {
    const int wave = t >> 6, lane = t & 63;
    const int k = bid * 4 + wave;
    const float* wr = W + (size_t)k * HDIM;
    float s[16];
    #pragma unroll
    for (int v = 0; v < 16; ++v) s[v] = 0.f;
    #pragma unroll
    for (int j = 0; j < 8; ++j) {
      const int h = lane + 64 * j;
      const float a = wr[h];
      const float4* wl = (const float4*)(Wsel + h * 16);
      const float4 q0 = wl[0], q1 = wl[1], q2 = wl[2], q3 = wl[3];
      s[0]  = fmaf(a, q0.x, s[0]);  s[1]  = fmaf(a, q0.y, s[1]);
      s[2]  = fmaf(a, q0.z, s[2]);  s[3]  = fmaf(a, q0.w, s[3]);
      s[4]  = fmaf(a, q1.x, s[4]);  s[5]  = fmaf(a, q1.y, s[5]);
      s[6]  = fmaf(a, q1.z, s[6]);  s[7]  = fmaf(a, q1.w, s[7]);
      s[8]  = fmaf(a, q2.x, s[8]);  s[9]  = fmaf(a, q2.y, s[9]);
      s[10] = fmaf(a, q2.z, s[10]); s[11] = fmaf(a, q2.w, s[11]);
      s[12] = fmaf(a, q3.x, s[12]); s[13] = fmaf(a, q3.y, s[13]);
      s[14] = fmaf(a, q3.z, s[14]); s[15] = fmaf(a, q3.w, s[15]);
    }
    #pragma unroll
    for (int off = 32; off > 0; off >>= 1) {
      #pragma unroll
      for (int v = 0; v < 16; ++v) s[v] += __shfl_xor(s[v], off, 64);
    }
    float mine = 0.f;
    #pragma unroll
    for (int v = 0; v < 16; ++v) mine = (lane == v) ? s[v] : mine;
    if (lane < 16) WcombT[lane * KDIM + k] = f2bf(mine * (1.f / 16.f));
  } else {
    for (int h = t; h < HDIM; h += 256) {
      float s = 0.f;
      #pragma unroll
      for (int v = 0; v < VDIM; ++v) s += bias[v * HDIM + h];
      bm[h] = s * (1.f / 16.f);
    }
    __syncthreads();
    int v = t & 15, sl = t >> 4;
    float s = 0.f;
    for (int h = sl * 32; h < sl * 32 + 32; ++h) s = fmaf(bm[h], Wsel[h * VDIM + v], s);
    part[sl][v] = s;
    __syncthreads();
    if (t < 16) {
      float s2 = bsel[t];
      #pragma unroll
      for (int i = 0; i < 16; ++i) s2 += part[i][t];
      bcomb[t] = s2;
    }
  }
}

// ---------------------------------------------------------------------------
// K2f: FULLY FUSED gate+scale+GEMM. Block M64 x N512, grid 256 = 1 block/CU.
// Phases: (1) stage bf16(x) unscaled -> LDS, keep reg copy
//         (2) logits: 16 MFMA/wave vs WcombT (L2-hot), partials -> LDS
//         (3) 64-thread softmax -> w[64][16] in LDS
//         (4) rescale A' from reg copy, write bias tail
//         (5) barrier-free 33-iter K-loop, B from L2 w/ 2-deep reg prefetch
__global__ __launch_bounds__(512, 2) void k2f_fused(
    const float* __restrict__ x, const unsigned short* __restrict__ WcombT,
    const float* __restrict__ bcomb, const unsigned short* __restrict__ Bt,
    float* __restrict__ C) {
  extern __shared__ unsigned short As[];          // [64][ASTR] bf16
  float* plog = (float*)((char*)As + PLOG_OFF);   // [2][4][16][17]
  float* wlds = (float*)((char*)As + WLDS_OFF);   // [64][16]

  const int t = threadIdx.x;
  const int rowb = blockIdx.x * 64;
  const int wave = t >> 6, lane = t & 63;
  const int mlane = lane & 15, quad = lane >> 4;

  // ---- Phase 1: stage bf16(x) unscaled; keep register copy.
  const int srow = t >> 3;              // 0..63
  const int sc = (t & 7) * 8;           // 0,8,...,56 ; covers k = sc + i*64
  u16x8 xreg[16];
  {
    const float* xr = x + (size_t)(rowb + srow) * KDIM + sc;
    unsigned short* aw = As + srow * ASTR + sc;
    #pragma unroll 4
    for (int i = 0; i < 16; ++i) {
      const float4 a0 = *(const float4*)(xr + i * 64);
      const float4 a1 = *(const float4*)(xr + i * 64 + 4);
      u16x8 u;
      u[0] = f2bf(a0.x); u[1] = f2bf(a0.y); u[2] = f2bf(a0.z); u[3] = f2bf(a0.w);
      u[4] = f2bf(a1.x); u[5] = f2bf(a1.y); u[6] = f2bf(a1.z); u[7] = f2bf(a1.w);
      xreg[i] = u;
      *(u16x8*)(aw + i * 64) = u;
    }
  }
  __syncthreads();   // barrier 1: As(x) visible

  // ---- Phase 2: partial logits. wave w: kh = w>>2 (K-half), rg = w&3 (rows)
  {
    const int kh = wave >> 2, rg = wave & 3;
    const unsigned short* al = As + (rg * 16 + mlane) * ASTR + kh * 512 + quad * 8;
    const unsigned short* bl = WcombT + mlane * KDIM + kh * 512 + quad * 8;
    f32x4 acc = {0.f, 0.f, 0.f, 0.f};
    #pragma unroll
    for (int kt = 0; kt < 16; ++kt) {
      bf16x8 a = *(const bf16x8*)al; al += 32;
      bf16x8 b = *(const bf16x8*)bl; bl += 32;
      acc = __builtin_amdgcn_mfma_f32_16x16x32_bf16(a, b, acc, 0, 0, 0);
    }
    // C layout: col(v)=lane&15, row=quad*4+r
    float* pl = plog + ((size_t)((kh * 4 + rg) * 16 + quad * 4) * 17 + mlane);
    #pragma unroll
    for (int r = 0; r < 4; ++r) pl[r * 17] = acc[r];
  }
  __syncthreads();   // barrier 2: plog visible

  // ---- Phase 3: softmax on 64 threads (row = t)
  if (t < 64) {
    const int rg = t >> 4, r = t & 15;
    const float* p0 = plog + ((size_t)(rg * 16 + r) * 17);
    const float* p1 = plog + ((size_t)((4 + rg) * 16 + r) * 17);
    float l[16];
    float mx = -1e30f;
    #pragma unroll
    for (int v = 0; v < 16; ++v) {
      l[v] = p0[v] + p1[v] + bcomb[v];
      mx = fmaxf(mx, l[v]);
    }
    float s = 0.f;
    #pragma unroll
    for (int v = 0; v < 16; ++v) { l[v] = __expf(l[v] - mx); s += l[v]; }
    const float inv = 1.f / s;
    float* wo = wlds + t * 16;
    #pragma unroll
    for (int v = 0; v < 16; ++v) wo[v] = l[v] * inv;
  }
  __syncthreads();   // barrier 3: wlds visible

  // ---- Phase 4: rescale A' from register copy; write bias tail
  {
    float wv[16];
    const float4* wq = (const float4*)(wlds + srow * 16);
    #pragma unroll
    for (int q = 0; q < 4; ++q) {
      const float4 f = wq[q];
      wv[4 * q + 0] = f.x; wv[4 * q + 1] = f.y; wv[4 * q + 2] = f.z; wv[4 * q + 3] = f.w;
    }
    unsigned short* aw = As + srow * ASTR + sc;
    #pragma unroll 4
    for (int i = 0; i < 16; ++i) {
      const float w = wv[i];              // v = k>>6 = i (sc < 64)
      const u16x8 a = xreg[i];
      u16x8 o;
      #pragma unroll
      for (int j = 0; j < 8; ++j) o[j] = f2bf(w * bf2f(a[j]));
      *(u16x8*)(aw + i * 64) = o;
    }
    if ((t & 7) < 4) {
      const int j8 = (t & 7) * 8;         // 0,8,16,24
      unsigned short o[8];
      #pragma unroll
      for (int jj = 0; jj < 8; ++jj)
        o[jj] = (j8 + jj < 16) ? f2bf(wv[j8 + jj]) : (unsigned short)0;
      *(u16x8*)(As + srow * ASTR + KDIM + j8) = *(const u16x8*)o;
    }
  }

  // ---- B pointers + 2-deep prefetch issued BEFORE the last barrier
  const int colb = wave * 64;
  const unsigned short* bp[4];
  #pragma unroll
  for (int j = 0; j < 4; ++j)
    bp[j] = Bt + (size_t)(colb + j * 16 + mlane) * KP + quad * 8;

  bf16x8 bv0[4], bv1[4];
  #pragma unroll
  for (int j = 0; j < 4; ++j) {
    bv0[j] = *(const bf16x8*)(bp[j]);
    bv1[j] = *(const bf16x8*)(bp[j] + 32);
    bp[j] += 64;
  }

  __syncthreads();   // barrier 4: A' final

  // ---- Phase 5: main GEMM K-loop (barrier-free)
  const unsigned short* ap[4];
  #pragma unroll
  for (int i = 0; i < 4; ++i)
    ap[i] = As + (i * 16 + mlane) * ASTR + quad * 8;

  f32x4 acc[4][4];
  const f32x4 z = {0.f, 0.f, 0.f, 0.f};
  #pragma unroll
  for (int i = 0; i < 4; ++i)
    #pragma unroll
    for (int j = 0; j < 4; ++j) acc[i][j] = z;

  #pragma unroll 1
  for (int kt = 0; kt < 33; ++kt) {
    bf16x8 bnext[4];
    if (kt < 31) {
      #pragma unroll
      for (int j = 0; j < 4; ++j) { bnext[j] = *(const bf16x8*)bp[j]; bp[j] += 32; }
    }
    bf16x8 av[4];
    #pragma unroll
    for (int i = 0; i < 4; ++i) { av[i] = *(const bf16x8*)ap[i]; ap[i] += 32; }
    #pragma unroll
    for (int i = 0; i < 4; ++i)
      #pragma unroll
      for (int j = 0; j < 4; ++j)
        acc[i][j] = __builtin_amdgcn_mfma_f32_16x16x32_bf16(av[i], bv0[j], acc[i][j], 0, 0, 0);
    #pragma unroll
    for (int j = 0; j < 4; ++j) { bv0[j] = bv1[j]; bv1[j] = bnext[j]; }
  }

  // ---- epilogue: C/D layout col=lane&15, row=quad*4+reg  [m89/m91]
  #pragma unroll
  for (int i = 0; i < 4; ++i)
    #pragma unroll
    for (int j = 0; j < 4; ++j)
      #pragma unroll
      for (int r = 0; r < 4; ++r) {
        const size_t row = (size_t)rowb + i * 16 + quad * 4 + r;
        const int col = colb + j * 16 + mlane;
        C[row * HDIM + col] = acc[i][j][r];
      }
}

// ---------------------------------------------------------------------------
extern "C" void kernel_launch(void* const* d_in, const int* in_sizes, int n_in,
                              void* d_out, int out_size, void* d_ws, size_t ws_size,
                              hipStream_t stream) {
  const float* x    = (const float*)d_in[0];   // [B, V, S] = [16384][1024] flat
  const float* W    = (const float*)d_in[1];   // [V, S, H] = [1024][512] flat
  const float* bias = (const float*)d_in[2];   // [V, H]
  const float* Wsel = (const float*)d_in[3];   // [H, V]
  const float* bsel = (const float*)d_in[4];   // [V]
  float* out = (float*)d_out;                  // [B, H] fp32

  char* ws = (char*)d_ws;
  unsigned short* Bt     = (unsigned short*)(ws);            // 512*1056*2 = 1,081,344 B
  unsigned short* WcombT = (unsigned short*)(ws + 1081344);  // 16*1024*2  =    32,768 B
  float*          bcomb  = (float*)(ws + 1114112);           // 16*4 (padded to 256)

  static int lds_set = 0;
  if (!lds_set) {
    hipFuncSetAttribute((const void*)k2f_fused,
                        hipFuncAttributeMaxDynamicSharedMemorySize, K2_LDS);
    lds_set = 1;
  }

  k0_prep<<<2369, 256, 0, stream>>>(W, bias, Wsel, bsel, Bt, WcombT, bcomb);
  k2f_fused<<<256, 512, K2_LDS, stream>>>(x, WcombT, bcomb, Bt, out);
}